// Round 3
// baseline (257.861 us; speedup 1.0000x reference)
//
#include <hip/hip_runtime.h>

// One thread per point. vm (64 B/point) is staged through LDS with
// fully-coalesced float4 loads: the direct pattern vm[4i+c] makes each
// load instruction touch 64 distinct cache lines (64 B lane stride),
// which serializes in the per-CU TA/L1 miss path. Staged pattern touches
// 16 lines/instr (perfect). Stores proved pattern-insensitive in R1->R2,
// so outputs are written directly (no LDS out-staging).
#define VMS 20  // LDS words per point row (16 data + 4 pad -> 2-way banks, free)

__global__ __launch_bounds__(256) void cov_proj_kernel(
    const float4* __restrict__ rot,     // (N,4) as float4
    const float*  __restrict__ mod,     // (1,)
    const float2* __restrict__ scale,   // (N,2) as float2
    const float*  __restrict__ p_k,     // (N,3)
    const float4* __restrict__ vm4,     // (N,16) viewed as float4[N*4]
    float*        __restrict__ out,     // (N,9)
    int n)
{
    __shared__ float s_vm[256 * VMS];   // 20 KiB

    const int t = threadIdx.x;
    const int base = blockIdx.x * 256;
    const int i = base + t;

    // --- Stage vm: block covers f4 indices [base*4, base*4 + 4*points) ---
    const int points = min(256, n - base);
    const int nf4 = points * 4;
    const size_t gbase = (size_t)base * 4;
    #pragma unroll
    for (int r = 0; r < 4; ++r) {
        int k = t + 256 * r;            // consecutive lanes -> consecutive f4s
        if (k < nf4) {
            float4 v = vm4[gbase + k];
            int p = k >> 2, c = k & 3;
            *(float4*)&s_vm[p * VMS + 4 * c] = v;  // 16B-aligned, <=2-way banks
        }
    }
    __syncthreads();

    if (i < n) {
        float4 q = rot[i];
        float r = q.x, x = q.y, y = q.z, z = q.w;
        float m = mod[0];
        float2 sc = scale[i];
        float s0 = m * sc.x;
        float s1 = m * sc.y;

        float R00 = 1.0f - 2.0f * (y * y + z * z);
        float R10 = 2.0f * (x * y + r * z);
        float R20 = 2.0f * (x * z - r * y);
        float R01 = 2.0f * (x * y - r * z);
        float R11 = 1.0f - 2.0f * (x * x + z * z);
        float R21 = 2.0f * (y * z + r * x);

        float u0 = s0 * R00, u1 = s0 * R10, u2 = s0 * R20;
        float v0 = s1 * R01, v1 = s1 * R11, v2 = s1 * R21;

        float p0 = p_k[3 * i + 0];
        float p1 = p_k[3 * i + 1];
        float p2 = p_k[3 * i + 2];

        // Read this point's vm row from LDS (banks: (VMS*t)%32 period-8, 2-way)
        const float* sv = &s_vm[t * VMS];
        float4 vm0 = *(const float4*)(sv + 0);
        float4 vm1 = *(const float4*)(sv + 4);
        float4 vm2 = *(const float4*)(sv + 8);
        float4 vm3 = *(const float4*)(sv + 12);

        float r1s1 = vm0.x * u0 + vm1.x * u1 + vm2.x * u2;
        float r1s2 = vm0.x * v0 + vm1.x * v1 + vm2.x * v2;
        float r2s1 = vm0.y * u0 + vm1.y * u1 + vm2.y * u2;
        float r2s2 = vm0.y * v0 + vm1.y * v1 + vm2.y * v2;
        float r3s1 = vm0.z * u0 + vm1.z * u1 + vm2.z * u2;
        float r3s2 = vm0.z * v0 + vm1.z * v1 + vm2.z * v2;

        float r1p = vm0.x * p0 + vm1.x * p1 + vm2.x * p2 + vm3.x;
        float r2p = vm0.y * p0 + vm1.y * p1 + vm2.y * p2 + vm3.y;
        float r3p = vm0.z * p0 + vm1.z * p1 + vm2.z * p2 + vm3.z;

        float* o = out + (size_t)9 * i;
        o[0] = r1s1;
        o[1] = r1s2;
        o[2] = r1p;
        o[3] = r2s1;
        o[4] = r2s2;
        o[5] = r2p;
        o[6] = r3s1;
        o[7] = r3s2;
        o[8] = r3p;
    }
}

extern "C" void kernel_launch(void* const* d_in, const int* in_sizes, int n_in,
                              void* d_out, int out_size, void* d_ws, size_t ws_size,
                              hipStream_t stream) {
    const float4* rot   = (const float4*)d_in[0];
    const float*  mod   = (const float*)d_in[1];
    const float2* scale = (const float2*)d_in[2];
    const float*  p_k   = (const float*)d_in[3];
    const float4* vm4   = (const float4*)d_in[4];
    float* out = (float*)d_out;

    int n = in_sizes[0] / 4;  // rot has N*4 elements
    int block = 256;
    int grid = (n + block - 1) / block;
    cov_proj_kernel<<<grid, block, 0, stream>>>(rot, mod, scale, p_k, vm4, out, n);
}